// Round 15
// baseline (68.792 us; speedup 1.0000x reference)
//
#include <hip/hip_runtime.h>
#include <hip/hip_fp16.h>

#define JN 17

typedef __fp16 h2v __attribute__((ext_vector_type(2)));
typedef _Float16 f16x8 __attribute__((ext_vector_type(8)));
typedef float f32x4 __attribute__((ext_vector_type(4)));

__device__ __forceinline__ float lrelu(float x){ return fmaxf(x, 0.01f*x); }
__device__ __forceinline__ unsigned h2u(h2v h){ unsigned u; __builtin_memcpy(&u, &h, 4); return u; }
__device__ __forceinline__ h2v u2h(unsigned u){ h2v h; __builtin_memcpy(&h, &u, 4); return h; }
__device__ __forceinline__ unsigned pkrtz(float a, float b){ return h2u(__builtin_amdgcn_cvt_pkrtz(a,b)); }
__device__ __forceinline__ float fdot2(unsigned a, unsigned b, float c){
    return __builtin_amdgcn_fdot2(u2h(a), u2h(b), c, false);
}
__device__ __forceinline__ f16x8 u4h8(uint4 u){ union{uint4 u; f16x8 h;} c; c.u=u; return c.h; }
__device__ __forceinline__ f32x4 mk4(float4 v){ f32x4 r; r[0]=v.x; r[1]=v.y; r[2]=v.z; r[3]=v.w; return r; }

// C(t0,t1) -> B-frag of next MFMA via cross-lane permute (values post-activation).
__device__ __forceinline__ f16x8 repack(f32x4 c0, f32x4 c1, int srcA, int srcB, bool selLo){
    unsigned pkA = pkrtz(c0[0], c0[1]);
    unsigned pkB = pkrtz(c0[2], c0[3]);
    unsigned pkC = pkrtz(c1[0], c1[1]);
    unsigned pkD = pkrtz(c1[2], c1[3]);
    unsigned rA0 = (unsigned)__shfl((int)pkA, srcA, 64);
    unsigned rB0 = (unsigned)__shfl((int)pkB, srcA, 64);
    unsigned rC0 = (unsigned)__shfl((int)pkC, srcA, 64);
    unsigned rD0 = (unsigned)__shfl((int)pkD, srcA, 64);
    unsigned rA1 = (unsigned)__shfl((int)pkA, srcB, 64);
    unsigned rB1 = (unsigned)__shfl((int)pkB, srcB, 64);
    unsigned rC1 = (unsigned)__shfl((int)pkC, srcB, 64);
    unsigned rD1 = (unsigned)__shfl((int)pkD, srcB, 64);
    uint4 u;
    u.x = selLo ? rA0 : rC0;
    u.y = selLo ? rB0 : rD0;
    u.z = selLo ? rA1 : rC1;
    u.w = selLo ? rB1 : rD1;
    return u4h8(u);
}

// ws header layout (u32 units), first 65536 bytes
#define OFF_PP    0
#define OFF_BQS   544
#define OFF_FQ    576
#define OFF_FD1   1088     // Wd1 A-frag, rows permuted to o's (h,h+16) dword order
#define OFF_FD2   1600     // Wd2 A-frag, standard row order
#define OFF_FUD   2112
#define OFF_FK    2624
#define OFF_FV    3136
#define OFF_TUP   3648
#define OFF_FUP   4192
#define HDR_BYTES 65536

#define KSTRIDE 276
#define QSTRIDE 132

// ---------------- prep ------------------------------------------------------
__global__ __launch_bounds__(256,1)
void prep_kernel(const void* __restrict__ mraw, const float* __restrict__ pos,
                 const float* __restrict__ Wup,
                 const float* __restrict__ Wud, const float* __restrict__ bud,
                 const float* __restrict__ Wq,  const float* __restrict__ bq,
                 const float* __restrict__ Wk,  const float* __restrict__ Wv,
                 const float* __restrict__ Wd1, const float* __restrict__ Wd2,
                 unsigned* __restrict__ ws32, unsigned* __restrict__ bmask, int B)
{
    int g = blockIdx.x*256 + threadIdx.x;
    const float isq = 0.17677669529663687f;

    const unsigned* mw = (const unsigned*)mraw;
    bool f3f=false, nz=false;
    #pragma unroll
    for (int i=0;i<17;i++){
        unsigned w = mw[i];
        if ((w>>24) == 0x3Fu) f3f = true;
        if (w & 0xFFFFFF00u)  nz  = true;
    }
    int mode = f3f ? 2 : (nz ? 1 : 0);
    if (g < B){
        unsigned bm = 0; size_t base = (size_t)g*JN;
        if (mode == 0){
            const int* mi = (const int*)mraw;
            #pragma unroll
            for (int j=0;j<JN;j++) if (mi[base+j] != 0) bm |= (1u<<j);
        } else if (mode == 1){
            const unsigned char* mb = (const unsigned char*)mraw;
            #pragma unroll
            for (int j=0;j<JN;j++) if (mb[base+j] != 0) bm |= (1u<<j);
        } else {
            const float* mf = (const float*)mraw;
            #pragma unroll
            for (int j=0;j<JN;j++) if (mf[base+j] != 0.f) bm |= (1u<<j);
        }
        bmask[g] = bm;
    }
    if (g < 544){
        int j = g >> 5, h = g & 31;
        float acc = bud[h];
        #pragma unroll
        for (int c=0;c<32;c++) acc = fmaf(pos[j*32+c], Wud[(32+c)*32 + h], acc);
        ((float*)ws32)[OFF_PP + g] = acc;
        int t = (g >> 4) & 1, c = g & 15;
        int col = j*32 + t*16 + c;
        ws32[OFF_TUP + g] = pkrtz(Wup[32*544 + col], Wup[33*544 + col]);
    }
    if (g < 32) ((float*)ws32)[OFF_BQS + g] = bq[g]*isq;
    if (g < 512){
        int t = g >> 8, rmn = g & 255, lane = rmn >> 2, i2 = rmn & 3;
        int k0 = (lane>>4)*8 + 2*i2, c = (lane&15) + 16*t;
        ws32[OFF_FUD + g] = pkrtz(Wud[k0*32 + c],     Wud[(k0+1)*32 + c]);
        ws32[OFF_FK  + g] = pkrtz(Wk [k0*32 + c],     Wk [(k0+1)*32 + c]);
        ws32[OFF_FV  + g] = pkrtz(Wv [k0*32 + c],     Wv [(k0+1)*32 + c]);
        ws32[OFF_FQ  + g] = pkrtz(Wq [k0*32 + c]*isq, Wq [(k0+1)*32 + c]*isq);
        // fd1: input rows follow o's dword order: element 2p -> ch p, 2p+1 -> ch p+16
        ws32[OFF_FD1 + g] = pkrtz(Wd1[(k0>>1)*32 + c], Wd1[(16 + (k0>>1))*32 + c]);
        ws32[OFF_FD2 + g] = pkrtz(Wd2[k0*32 + c],     Wd2[(k0+1)*32 + c]);
    }
    if (g < 8704){
        int j = g >> 9, r = g & 511, t = r >> 8, rr = r & 255, lane = rr >> 2, i2 = rr & 3;
        int k0 = (lane>>4)*8 + 2*i2;
        int col = j*32 + (lane&15) + 16*t;
        ws32[OFF_FUP + g] = pkrtz(Wup[k0*544 + col], Wup[(k0+1)*544 + col]);
    }
}

// ---------------- fused kernel: 16 samples / block (4 waves) -----------------
// Phase1 (transposed MFMA) -> LDS. Phase2a: wave w handles samples 4w..4w+3,
// scores + PV as per-sample MFMAs (k/v read ONCE per wave). Phase2b: batched
// d1/d2 MFMAs over 128 (s,q) rows.
__global__ __launch_bounds__(256,3)
void fused_kernel(const float* __restrict__ x, const unsigned* __restrict__ bmask,
                  const unsigned* __restrict__ ws32,
                  const float* __restrict__ bup, const float* __restrict__ bk,
                  const float* __restrict__ bv,  const float* __restrict__ bd1,
                  const float* __restrict__ bd2, const float* __restrict__ Ws,
                  const float* __restrict__ bs,  float* __restrict__ out, int B)
{
    __shared__ unsigned ksl[16*KSTRIDE];
    __shared__ unsigned vsl[16*KSTRIDE];
    __shared__ unsigned qsl[16*QSTRIDE];
    __shared__ unsigned usl[16*QSTRIDE];

    const int tid = threadIdx.x;
    const int wid = tid >> 6, wl = tid & 63;
    const int sb  = blockIdx.x * 16;
    const int s   = wl & 15, g4 = wl >> 4;
    const int smax = B - 1;

    // ---------------- phase 1 (round-10/13, verified) ----------------
    {
        int sA = sb + s; if (sA > smax) sA = smax;
        f16x8 ax;
        {
            const float* xr = x + (size_t)sA*34 + g4*8;
            float2 a0 = *(const float2*)(xr);
            float2 a1 = *(const float2*)(xr+2);
            float2 a2 = *(const float2*)(xr+4);
            float2 a3 = *(const float2*)(xr+6);
            uint4 u; u.x=pkrtz(a0.x,a0.y); u.y=pkrtz(a1.x,a1.y);
            u.z=pkrtz(a2.x,a2.y); u.w=pkrtz(a3.x,a3.y);
            ax = u4h8(u);
        }
        const unsigned bm = bmask[sA];
        float2 xt2 = *(const float2*)(x + (size_t)sA*34 + 32);
        const unsigned xtp = pkrtz(xt2.x, xt2.y);

        const uint4* wsu4 = (const uint4*)ws32;
        f16x8 fud0 = u4h8(wsu4[OFF_FUD/4 + wl]);
        f16x8 fud1 = u4h8(wsu4[OFF_FUD/4 + 64 + wl]);
        f16x8 fk0  = u4h8(wsu4[OFF_FK/4  + wl]);
        f16x8 fk1  = u4h8(wsu4[OFF_FK/4  + 64 + wl]);
        f16x8 fv0  = u4h8(wsu4[OFF_FV/4  + wl]);
        f16x8 fv1  = u4h8(wsu4[OFF_FV/4  + 64 + wl]);
        f16x8 fq0  = u4h8(wsu4[OFF_FQ/4  + wl]);
        f16x8 fq1  = u4h8(wsu4[OFF_FQ/4  + 64 + wl]);

        const float* ppf = (const float*)ws32;
        float4 bk0 = *(const float4*)(bk + g4*4);
        float4 bk1 = *(const float4*)(bk + 16 + g4*4);
        float4 bv0 = *(const float4*)(bv + g4*4);
        float4 bv1 = *(const float4*)(bv + 16 + g4*4);
        float4 bq0 = *(const float4*)(ppf + OFF_BQS + g4*4);
        float4 bq1 = *(const float4*)(ppf + OFF_BQS + 16 + g4*4);

        const int srcA = s + 32*(g4 & 1);
        const int srcB = srcA + 16;
        const bool selLo = (g4 < 2);

        const int njl = (wid == 3) ? 5 : 4;
        for (int jj = 0; jj < njl; jj++){
            const int j = (jj < 4) ? (wid + jj*4) : 16;
            f16x8 fup0 = u4h8(wsu4[OFF_FUP/4 + j*128 + wl]);
            f16x8 fup1 = u4h8(wsu4[OFF_FUP/4 + j*128 + 64 + wl]);
            float4 bu0 = *(const float4*)(bup + j*32 + g4*4);
            float4 bu1 = *(const float4*)(bup + j*32 + 16 + g4*4);
            float4 pp0 = *(const float4*)(ppf + OFF_PP + j*32 + g4*4);
            float4 pp1 = *(const float4*)(ppf + OFF_PP + j*32 + 16 + g4*4);
            uint4 tu0 = *(const uint4*)(ws32 + OFF_TUP + j*32 + g4*4);
            uint4 tu1 = *(const uint4*)(ws32 + OFF_TUP + j*32 + 16 + g4*4);

            f32x4 up0, up1;
            up0[0] = fdot2(xtp, tu0.x, bu0.x); up0[1] = fdot2(xtp, tu0.y, bu0.y);
            up0[2] = fdot2(xtp, tu0.z, bu0.z); up0[3] = fdot2(xtp, tu0.w, bu0.w);
            up1[0] = fdot2(xtp, tu1.x, bu1.x); up1[1] = fdot2(xtp, tu1.y, bu1.y);
            up1[2] = fdot2(xtp, tu1.z, bu1.z); up1[3] = fdot2(xtp, tu1.w, bu1.w);
            up0 = __builtin_amdgcn_mfma_f32_16x16x32_f16(fup0, ax, up0, 0,0,0);
            up1 = __builtin_amdgcn_mfma_f32_16x16x32_f16(fup1, ax, up1, 0,0,0);
            #pragma unroll
            for (int r=0;r<4;r++){ up0[r] = lrelu(up0[r]); up1[r] = lrelu(up1[r]); }

            const bool occ = !((bm>>j)&1u);
            const int rk = __popc((~bm) & ((1u<<j)-1u));
            if (occ){
                int rotq = (rk + s + (s>>2)) & 3;
                uint4 u;
                u.x = pkrtz(up0[0], up1[0]); u.y = pkrtz(up0[1], up1[1]);
                u.z = pkrtz(up0[2], up1[2]); u.w = pkrtz(up0[3], up1[3]);
                *(uint4*)&usl[s*QSTRIDE + rk*16 + ((g4 + rotq)&3)*4] = u;
            }
            f16x8 aup = repack(up0, up1, srcA, srcB, selLo);

            f32x4 uu0 = mk4(pp0), uu1 = mk4(pp1);
            uu0 = __builtin_amdgcn_mfma_f32_16x16x32_f16(fud0, aup, uu0, 0,0,0);
            uu1 = __builtin_amdgcn_mfma_f32_16x16x32_f16(fud1, aup, uu1, 0,0,0);
            #pragma unroll
            for (int r=0;r<4;r++){ uu0[r] = lrelu(uu0[r]); uu1[r] = lrelu(uu1[r]); }
            f16x8 auu = repack(uu0, uu1, srcA, srcB, selLo);

            f32x4 kk0 = mk4(bk0), kk1 = mk4(bk1);
            f32x4 vv0 = mk4(bv0), vv1 = mk4(bv1);
            f32x4 qq0 = mk4(bq0), qq1 = mk4(bq1);
            kk0 = __builtin_amdgcn_mfma_f32_16x16x32_f16(fk0, auu, kk0, 0,0,0);
            kk1 = __builtin_amdgcn_mfma_f32_16x16x32_f16(fk1, auu, kk1, 0,0,0);
            vv0 = __builtin_amdgcn_mfma_f32_16x16x32_f16(fv0, auu, vv0, 0,0,0);
            vv1 = __builtin_amdgcn_mfma_f32_16x16x32_f16(fv1, auu, vv1, 0,0,0);
            qq0 = __builtin_amdgcn_mfma_f32_16x16x32_f16(fq0, auu, qq0, 0,0,0);
            qq1 = __builtin_amdgcn_mfma_f32_16x16x32_f16(fq1, auu, qq1, 0,0,0);

            const int rot = (j + s + (s>>2)) & 3;
            const int grp = ((g4 + rot)&3)*4;
            uint4 kp, vp;
            kp.x = pkrtz(kk0[0], kk1[0]); kp.y = pkrtz(kk0[1], kk1[1]);
            kp.z = pkrtz(kk0[2], kk1[2]); kp.w = pkrtz(kk0[3], kk1[3]);
            vp.x = pkrtz(vv0[0], vv1[0]); vp.y = pkrtz(vv0[1], vv1[1]);
            vp.z = pkrtz(vv0[2], vv1[2]); vp.w = pkrtz(vv0[3], vv1[3]);
            *(uint4*)&ksl[s*KSTRIDE + j*16 + grp] = kp;
            *(uint4*)&vsl[s*KSTRIDE + j*16 + grp] = vp;
            if (occ){
                int rotq = (rk + s + (s>>2)) & 3;
                uint4 qp4;
                qp4.x = pkrtz(qq0[0], qq1[0]); qp4.y = pkrtz(qq0[1], qq1[1]);
                qp4.z = pkrtz(qq0[2], qq1[2]); qp4.w = pkrtz(qq0[3], qq1[3]);
                *(uint4*)&qsl[s*QSTRIDE + rk*16 + ((g4 + rotq)&3)*4] = qp4;
            }
        }
    }
    __syncthreads();

    // ---------------- phase 2a: wave wid -> samples 4wid..4wid+3 -------------
    // scores: S = mfma(k-frag, q-frag); key16 via fdot2; softmax wave-parallel;
    // PV: o = mfma(att-frag, v-frag x2). k/v read once per wave per sample.
    const int lq = wl & 15;      // col index (query for scores; h for PV)
    f32x4 oT0_0, oT0_1, oT0_2, oT0_3;    // o tile0 per sample (static names)
    f32x4 oT1_0, oT1_1, oT1_2, oT1_3;    // o tile1
    #pragma unroll
    for (int it=0; it<4; ++it){
        const int smp = (wid<<2) + it;
        // A-frag: k row = key = lq, logical dwords g4*4..+3 (rot-swizzled)
        int rotk = (lq + smp + (smp>>2)) & 3;
        uint4 kA4 = *(const uint4*)&ksl[smp*KSTRIDE + lq*16 + ((g4 + rotk)&3)*4];
        // key16 row (broadcast read)
        int rot16 = (16 + smp + (smp>>2)) & 3;
        uint4 k164 = *(const uint4*)&ksl[smp*KSTRIDE + 16*16 + ((g4 + rot16)&3)*4];
        // B-frag: q col = lq (<8), zero else
        uint4 qB4 = make_uint4(0u,0u,0u,0u);
        if (lq < 8){
            int rotq = (lq + smp + (smp>>2)) & 3;
            qB4 = *(const uint4*)&qsl[smp*QSTRIDE + lq*16 + ((g4 + rotq)&3)*4];
        }
        f32x4 S = {0.f,0.f,0.f,0.f};
        S = __builtin_amdgcn_mfma_f32_16x16x32_f16(u4h8(kA4), u4h8(qB4), S, 0,0,0);
        // key16 score (per col q)
        float p16 = 0.f;
        p16 = fdot2(qB4.x, k164.x, p16); p16 = fdot2(qB4.y, k164.y, p16);
        p16 = fdot2(qB4.z, k164.z, p16); p16 = fdot2(qB4.w, k164.w, p16);
        p16 += __shfl_xor(p16, 16, 64);
        p16 += __shfl_xor(p16, 32, 64);
        // softmax over 17 keys (regs = keys g4*4+r; cross-g4 reduce)
        float m4 = fmaxf(fmaxf(S[0],S[1]), fmaxf(S[2],S[3]));
        m4 = fmaxf(m4, __shfl_xor(m4, 16, 64));
        m4 = fmaxf(m4, __shfl_xor(m4, 32, 64));
        float m = fmaxf(m4, p16);
        float e0 = __expf(S[0]-m), e1 = __expf(S[1]-m);
        float e2 = __expf(S[2]-m), e3 = __expf(S[3]-m);
        float es = (e0+e1)+(e2+e3);
        es += __shfl_xor(es, 16, 64);
        es += __shfl_xor(es, 32, 64);
        float e16 = __expf(p16 - m);
        float ri = 1.0f / (es + e16);
        unsigned p01 = pkrtz(e0*ri, e1*ri);
        unsigned p23 = pkrtz(e2*ri, e3*ri);
        unsigned a16 = pkrtz(e16*ri, 0.f);
        // att A-frag: row=q=lq, k-dim dword i2 = keys (g4*8+2i2, +1)
        int sA2 = lq + 32*(g4 & 1);
        int sB2 = sA2 + 16;
        unsigned d0 = (unsigned)__shfl((int)p01, sA2, 64);
        unsigned d1 = (unsigned)__shfl((int)p23, sA2, 64);
        unsigned d2 = (unsigned)__shfl((int)p01, sB2, 64);
        unsigned d3 = (unsigned)__shfl((int)p23, sB2, 64);
        bool gLo = (g4 < 2);
        d0 = gLo ? d0 : ((g4 == 2) ? a16 : 0u);
        d1 = gLo ? d1 : 0u;
        d2 = gLo ? d2 : 0u;
        d3 = gLo ? d3 : 0u;
        f16x8 attA = u4h8(make_uint4(d0,d1,d2,d3));
        // v B-frag: col = h = lq (+16 tile1), dword i2 = keys (g4*8+2i2, +1)
        unsigned b00, b01, b02, b03, b10, b11, b12, b13;
        {
            int phys = (lq & 3);
            int lg = lq >> 2;
            unsigned ra, rb;
            int ka, kb, rota, rotb;
            // i2 = 0
            ka = g4*8;     kb = ka+1;
            ra = 0u; rb = 0u;
            if (ka < JN){ rota = (ka + smp + (smp>>2)) & 3;
                ra = vsl[smp*KSTRIDE + ka*16 + ((lg + rota)&3)*4 + phys]; }
            if (kb < JN){ rotb = (kb + smp + (smp>>2)) & 3;
                rb = vsl[smp*KSTRIDE + kb*16 + ((lg + rotb)&3)*4 + phys]; }
            b00 = (ra & 0xFFFFu) | (rb << 16);
            b10 = (ra >> 16) | (rb & 0xFFFF0000u);
            // i2 = 1
            ka = g4*8+2;   kb = ka+1;
            ra = 0u; rb = 0u;
            if (ka < JN){ rota = (ka + smp + (smp>>2)) & 3;
                ra = vsl[smp*KSTRIDE + ka*16 + ((lg + rota)&3)*4 + phys]; }
            if (kb < JN){ rotb = (kb + smp + (smp>>2)) & 3;
                rb = vsl[smp*KSTRIDE + kb*16 + ((lg + rotb)&3)*4 + phys]; }
            b01 = (ra & 0xFFFFu) | (rb << 16);
            b11 = (ra >> 16) | (rb & 0xFFFF0000u);
            // i2 = 2
            ka = g4*8+4;   kb = ka+1;
            ra = 0u; rb = 0u;
            if (ka < JN){ rota = (ka + smp + (smp>>2)) & 3;
                ra = vsl[smp*KSTRIDE + ka*16 + ((lg + rota)&3)*4 + phys]; }
            if (kb < JN){ rotb = (kb + smp + (smp>>2)) & 3;
                rb = vsl[smp*KSTRIDE + kb*16 + ((lg + rotb)&3)*4 + phys]; }
            b02 = (ra & 0xFFFFu) | (rb << 16);
            b12 = (ra >> 16) | (rb & 0xFFFF0000u);
            // i2 = 3
            ka = g4*8+6;   kb = ka+1;
            ra = 0u; rb = 0u;
            if (ka < JN){ rota = (ka + smp + (smp>>2)) & 3;
                ra = vsl[smp*KSTRIDE + ka*16 + ((lg + rota)&3)*4 + phys]; }
            if (kb < JN){ rotb = (kb + smp + (smp>>2)) & 3;
                rb = vsl[smp*KSTRIDE + kb*16 + ((lg + rotb)&3)*4 + phys]; }
            b03 = (ra & 0xFFFFu) | (rb << 16);
            b13 = (ra >> 16) | (rb & 0xFFFF0000u);
        }
        f16x8 vB0 = u4h8(make_uint4(b00,b01,b02,b03));
        f16x8 vB1 = u4h8(make_uint4(b10,b11,b12,b13));
        f32x4 z4 = {0.f,0.f,0.f,0.f};
        f32x4 r0 = __builtin_amdgcn_mfma_f32_16x16x32_f16(attA, vB0, z4, 0,0,0);
        f32x4 r1 = __builtin_amdgcn_mfma_f32_16x16x32_f16(attA, vB1, z4, 0,0,0);
        if (it==0){ oT0_0 = r0; oT1_0 = r1; }
        else if (it==1){ oT0_1 = r0; oT1_1 = r1; }
        else if (it==2){ oT0_2 = r0; oT1_2 = r1; }
        else { oT0_3 = r0; oT1_3 = r1; }
    }
    __syncthreads();       // all ksl/vsl/qsl reads complete -> qsl reusable
    // store o rows into qsl: rowg = smp*8 + q, q = g4*4+reg (g4<2 lanes only)
    if (g4 < 2){
        #pragma unroll
        for (int it=0; it<4; ++it){
            const int smp = (wid<<2) + it;
            f32x4 t0 = (it==0)?oT0_0:(it==1)?oT0_1:(it==2)?oT0_2:oT0_3;
            f32x4 t1 = (it==0)?oT1_0:(it==1)?oT1_1:(it==2)?oT1_2:oT1_3;
            #pragma unroll
            for (int reg=0; reg<4; ++reg){
                int qq = g4*4 + reg;
                int rowg = smp*8 + qq;
                int roto = (rowg>>1)&3;
                qsl[rowg*16 + (((lq>>2) + roto)&3)*4 + (lq&3)] = pkrtz(t0[reg], t1[reg]);
            }
        }
    }
    __syncthreads();

    // ---------------- phase 2b: all 4 waves, d1/d2 as batched MFMAs ----------
    {
        const int rid = wl & 15, g4b = wl >> 4;
        const uint4* wsu4 = (const uint4*)ws32;
        f16x8 fd1_0 = u4h8(wsu4[OFF_FD1/4 + wl]);
        f16x8 fd1_1 = u4h8(wsu4[OFF_FD1/4 + 64 + wl]);
        f16x8 fd2_0 = u4h8(wsu4[OFF_FD2/4 + wl]);
        f16x8 fd2_1 = u4h8(wsu4[OFF_FD2/4 + 64 + wl]);
        float4 bd10 = *(const float4*)(bd1 + g4b*4);
        float4 bd11 = *(const float4*)(bd1 + 16 + g4b*4);
        float4 bd20 = *(const float4*)(bd2 + g4b*4);
        float4 bd21 = *(const float4*)(bd2 + 16 + g4b*4);
        float4 ws0  = *(const float4*)(Ws + g4b*4);
        float4 ws1  = *(const float4*)(Ws + 16 + g4b*4);
        const float bsv = bs[0];
        const int srcA = rid + 32*(g4b & 1);
        const int srcB = srcA + 16;
        const bool selLo = (g4b < 2);

        #pragma unroll
        for (int gg=0; gg<2; gg++){
            const int rowg = (wid*2 + gg)*16 + rid;       // 0..127
            int roto = (rowg>>1)&3;
            f16x8 bo = u4h8(*(const uint4*)&qsl[rowg*16 + ((g4b + roto)&3)*4]);

            f32x4 t0 = mk4(bd10), t1 = mk4(bd11);
            t0 = __builtin_amdgcn_mfma_f32_16x16x32_f16(fd1_0, bo, t0, 0,0,0);
            t1 = __builtin_amdgcn_mfma_f32_16x16x32_f16(fd1_1, bo, t1, 0,0,0);
            #pragma unroll
            for (int r=0;r<4;r++){ t0[r] = lrelu(t0[r]); t1[r] = lrelu(t1[r]); }
            f16x8 bt = repack(t0, t1, srcA, srcB, selLo);

            const int s2b = rowg >> 3, qb = rowg & 7;
            int rotq = (qb + s2b + (s2b>>2)) & 3;
            uint4 ur = *(const uint4*)&usl[s2b*QSTRIDE + qb*16 + ((g4b + rotq)&3)*4];
            unsigned urr[4] = {ur.x, ur.y, ur.z, ur.w};
            f32x4 z0, z1;
            {
                h2v r0 = u2h(urr[0]), r1 = u2h(urr[1]), r2 = u2h(urr[2]), r3 = u2h(urr[3]);
                z0[0] = (float)r0.x + bd20.x; z1[0] = (float)r0.y + bd21.x;
                z0[1] = (float)r1.x + bd20.y; z1[1] = (float)r1.y + bd21.y;
                z0[2] = (float)r2.x + bd20.z; z1[2] = (float)r2.y + bd21.z;
                z0[3] = (float)r3.x + bd20.w; z1[3] = (float)r3.y + bd21.w;
            }
            z0 = __builtin_amdgcn_mfma_f32_16x16x32_f16(fd2_0, bt, z0, 0,0,0);
            z1 = __builtin_amdgcn_mfma_f32_16x16x32_f16(fd2_1, bt, z1, 0,0,0);

            float yp = z0[0]*ws0.x + z0[1]*ws0.y + z0[2]*ws0.z + z0[3]*ws0.w
                     + z1[0]*ws1.x + z1[1]*ws1.y + z1[2]*ws1.z + z1[3]*ws1.w;
            yp += __shfl_xor(yp, 16, 64);
            yp += __shfl_xor(yp, 32, 64);
            if (g4b == 0 && sb + s2b < B){
                float y = yp + bsv;
                out[((size_t)(sb + s2b))*8 + qb] = 1.0f/(1.0f + __expf(-y));
            }
        }
    }
}

extern "C" void kernel_launch(void* const* d_in, const int* in_sizes, int n_in,
                              void* d_out, int out_size, void* d_ws, size_t ws_size,
                              hipStream_t stream) {
    (void)n_in; (void)out_size; (void)ws_size;
    const float* x   = (const float*)d_in[0];
    const void*  m   = d_in[1];
    const float* pos = (const float*)d_in[2];
    const float* Wup = (const float*)d_in[3];  const float* bup = (const float*)d_in[4];
    const float* Wud = (const float*)d_in[5];  const float* bud = (const float*)d_in[6];
    const float* Wq  = (const float*)d_in[7];  const float* bq  = (const float*)d_in[8];
    const float* Wk  = (const float*)d_in[9];  const float* bk  = (const float*)d_in[10];
    const float* Wv  = (const float*)d_in[11]; const float* bv  = (const float*)d_in[12];
    const float* Wd1 = (const float*)d_in[13]; const float* bd1 = (const float*)d_in[14];
    const float* Wd2 = (const float*)d_in[15]; const float* bd2 = (const float*)d_in[16];
    const float* Ws  = (const float*)d_in[17]; const float* bs  = (const float*)d_in[18];
    float* out = (float*)d_out;
    int B = in_sizes[0] / (JN*2);

    unsigned char* wsb = (unsigned char*)d_ws;
    unsigned* ws32  = (unsigned*)wsb;
    unsigned* bmask = (unsigned*)(wsb + HDR_BYTES);

    prep_kernel<<<(B+255)/256, 256, 0, stream>>>(m, pos, Wup, Wud, bud, Wq, bq,
                                                 Wk, Wv, Wd1, Wd2, ws32, bmask, B);
    fused_kernel<<<(B+15)/16, 256, 0, stream>>>(x, bmask, ws32, bup, bk, bv,
                                                bd1, bd2, Ws, bs, out, B);
}

// Round 16
// 64.301 us; speedup vs baseline: 1.0698x; 1.0698x over previous
//
#include <hip/hip_runtime.h>
#include <hip/hip_fp16.h>

#define JN 17

typedef __fp16 h2v __attribute__((ext_vector_type(2)));
typedef _Float16 f16x8 __attribute__((ext_vector_type(8)));
typedef float f32x4 __attribute__((ext_vector_type(4)));

__device__ __forceinline__ float lrelu(float x){ return fmaxf(x, 0.01f*x); }
__device__ __forceinline__ unsigned h2u(h2v h){ unsigned u; __builtin_memcpy(&u, &h, 4); return u; }
__device__ __forceinline__ h2v u2h(unsigned u){ h2v h; __builtin_memcpy(&h, &u, 4); return h; }
__device__ __forceinline__ unsigned pkrtz(float a, float b){ return h2u(__builtin_amdgcn_cvt_pkrtz(a,b)); }
__device__ __forceinline__ float fdot2(unsigned a, unsigned b, float c){
    return __builtin_amdgcn_fdot2(u2h(a), u2h(b), c, false);
}
__device__ __forceinline__ unsigned pkfma(unsigned a, unsigned b, unsigned c){
    h2v r = u2h(a)*u2h(b) + u2h(c);
    return h2u(r);
}
__device__ __forceinline__ f16x8 u4h8(uint4 u){ union{uint4 u; f16x8 h;} c; c.u=u; return c.h; }
__device__ __forceinline__ f32x4 mk4(float4 v){ f32x4 r; r[0]=v.x; r[1]=v.y; r[2]=v.z; r[3]=v.w; return r; }

// C(t0,t1) -> B-frag of next MFMA via cross-lane permute (values post-activation).
__device__ __forceinline__ f16x8 repack(f32x4 c0, f32x4 c1, int srcA, int srcB, bool selLo){
    unsigned pkA = pkrtz(c0[0], c0[1]);
    unsigned pkB = pkrtz(c0[2], c0[3]);
    unsigned pkC = pkrtz(c1[0], c1[1]);
    unsigned pkD = pkrtz(c1[2], c1[3]);
    unsigned rA0 = (unsigned)__shfl((int)pkA, srcA, 64);
    unsigned rB0 = (unsigned)__shfl((int)pkB, srcA, 64);
    unsigned rC0 = (unsigned)__shfl((int)pkC, srcA, 64);
    unsigned rD0 = (unsigned)__shfl((int)pkD, srcA, 64);
    unsigned rA1 = (unsigned)__shfl((int)pkA, srcB, 64);
    unsigned rB1 = (unsigned)__shfl((int)pkB, srcB, 64);
    unsigned rC1 = (unsigned)__shfl((int)pkC, srcB, 64);
    unsigned rD1 = (unsigned)__shfl((int)pkD, srcB, 64);
    uint4 u;
    u.x = selLo ? rA0 : rC0;
    u.y = selLo ? rB0 : rD0;
    u.z = selLo ? rA1 : rC1;
    u.w = selLo ? rB1 : rD1;
    return u4h8(u);
}

// ws header layout (u32 units), first 65536 bytes
#define OFF_PP    0
#define OFF_BQS   544
#define OFF_FQ    576
#define OFF_FD1   1088     // Wd1 A-frag, rows permuted to o's (h,h+16) dword order
#define OFF_FD2   1600     // Wd2 A-frag, standard row order
#define OFF_FUD   2112
#define OFF_FK    2624
#define OFF_FV    3136
#define OFF_TUP   3648
#define OFF_FUP   4192
#define HDR_BYTES 65536

#define KSTRIDE 276
#define QSTRIDE 132

// ---------------- prep ------------------------------------------------------
__global__ __launch_bounds__(256,1)
void prep_kernel(const void* __restrict__ mraw, const float* __restrict__ pos,
                 const float* __restrict__ Wup,
                 const float* __restrict__ Wud, const float* __restrict__ bud,
                 const float* __restrict__ Wq,  const float* __restrict__ bq,
                 const float* __restrict__ Wk,  const float* __restrict__ Wv,
                 const float* __restrict__ Wd1, const float* __restrict__ Wd2,
                 unsigned* __restrict__ ws32, unsigned* __restrict__ bmask, int B)
{
    int g = blockIdx.x*256 + threadIdx.x;
    const float isq = 0.17677669529663687f;

    const unsigned* mw = (const unsigned*)mraw;
    bool f3f=false, nz=false;
    #pragma unroll
    for (int i=0;i<17;i++){
        unsigned w = mw[i];
        if ((w>>24) == 0x3Fu) f3f = true;
        if (w & 0xFFFFFF00u)  nz  = true;
    }
    int mode = f3f ? 2 : (nz ? 1 : 0);
    if (g < B){
        unsigned bm = 0; size_t base = (size_t)g*JN;
        if (mode == 0){
            const int* mi = (const int*)mraw;
            #pragma unroll
            for (int j=0;j<JN;j++) if (mi[base+j] != 0) bm |= (1u<<j);
        } else if (mode == 1){
            const unsigned char* mb = (const unsigned char*)mraw;
            #pragma unroll
            for (int j=0;j<JN;j++) if (mb[base+j] != 0) bm |= (1u<<j);
        } else {
            const float* mf = (const float*)mraw;
            #pragma unroll
            for (int j=0;j<JN;j++) if (mf[base+j] != 0.f) bm |= (1u<<j);
        }
        bmask[g] = bm;
    }
    if (g < 544){
        int j = g >> 5, h = g & 31;
        float acc = bud[h];
        #pragma unroll
        for (int c=0;c<32;c++) acc = fmaf(pos[j*32+c], Wud[(32+c)*32 + h], acc);
        ((float*)ws32)[OFF_PP + g] = acc;
        int t = (g >> 4) & 1, c = g & 15;
        int col = j*32 + t*16 + c;
        ws32[OFF_TUP + g] = pkrtz(Wup[32*544 + col], Wup[33*544 + col]);
    }
    if (g < 32) ((float*)ws32)[OFF_BQS + g] = bq[g]*isq;
    if (g < 512){
        int t = g >> 8, rmn = g & 255, lane = rmn >> 2, i2 = rmn & 3;
        int k0 = (lane>>4)*8 + 2*i2, c = (lane&15) + 16*t;
        ws32[OFF_FUD + g] = pkrtz(Wud[k0*32 + c],     Wud[(k0+1)*32 + c]);
        ws32[OFF_FK  + g] = pkrtz(Wk [k0*32 + c],     Wk [(k0+1)*32 + c]);
        ws32[OFF_FV  + g] = pkrtz(Wv [k0*32 + c],     Wv [(k0+1)*32 + c]);
        ws32[OFF_FQ  + g] = pkrtz(Wq [k0*32 + c]*isq, Wq [(k0+1)*32 + c]*isq);
        // fd1: input rows follow o's dword order: element 2p -> ch p, 2p+1 -> ch p+16
        ws32[OFF_FD1 + g] = pkrtz(Wd1[(k0>>1)*32 + c], Wd1[(16 + (k0>>1))*32 + c]);
        ws32[OFF_FD2 + g] = pkrtz(Wd2[k0*32 + c],     Wd2[(k0+1)*32 + c]);
    }
    if (g < 8704){
        int j = g >> 9, r = g & 511, t = r >> 8, rr = r & 255, lane = rr >> 2, i2 = rr & 3;
        int k0 = (lane>>4)*8 + 2*i2;
        int col = j*32 + (lane&15) + 16*t;
        ws32[OFF_FUP + g] = pkrtz(Wup[k0*544 + col], Wup[(k0+1)*544 + col]);
    }
}

// ---------------- fused kernel: 16 samples / block (4 waves) -----------------
// Phase1 (transposed MFMA, 2-way j-interleave for ILP) -> LDS.
// Phase2a (256 lanes = 128 pairs x 2 key-halves) -> o partials.
// Phase2b: batched d1/d2 MFMAs over 128 rows.
__global__ __launch_bounds__(256,3)
void fused_kernel(const float* __restrict__ x, const unsigned* __restrict__ bmask,
                  const unsigned* __restrict__ ws32,
                  const float* __restrict__ bup, const float* __restrict__ bk,
                  const float* __restrict__ bv,  const float* __restrict__ bd1,
                  const float* __restrict__ bd2, const float* __restrict__ Ws,
                  const float* __restrict__ bs,  float* __restrict__ out, int B)
{
    __shared__ unsigned ksl[16*KSTRIDE];
    __shared__ unsigned vsl[16*KSTRIDE];
    __shared__ unsigned qsl[16*QSTRIDE];
    __shared__ unsigned usl[16*QSTRIDE];

    const int tid = threadIdx.x;
    const int wid = tid >> 6, wl = tid & 63;
    const int sb  = blockIdx.x * 16;
    const int s   = wl & 15, g4 = wl >> 4;
    const int smax = B - 1;

    // ---------------- phase 1: 2-way j-interleaved ----------------
    {
        int sA = sb + s; if (sA > smax) sA = smax;
        f16x8 ax;
        {
            const float* xr = x + (size_t)sA*34 + g4*8;
            float2 a0 = *(const float2*)(xr);
            float2 a1 = *(const float2*)(xr+2);
            float2 a2 = *(const float2*)(xr+4);
            float2 a3 = *(const float2*)(xr+6);
            uint4 u; u.x=pkrtz(a0.x,a0.y); u.y=pkrtz(a1.x,a1.y);
            u.z=pkrtz(a2.x,a2.y); u.w=pkrtz(a3.x,a3.y);
            ax = u4h8(u);
        }
        const unsigned bm = bmask[sA];
        float2 xt2 = *(const float2*)(x + (size_t)sA*34 + 32);
        const unsigned xtp = pkrtz(xt2.x, xt2.y);

        const uint4* wsu4 = (const uint4*)ws32;
        f16x8 fud0 = u4h8(wsu4[OFF_FUD/4 + wl]);
        f16x8 fud1 = u4h8(wsu4[OFF_FUD/4 + 64 + wl]);
        f16x8 fk0  = u4h8(wsu4[OFF_FK/4  + wl]);
        f16x8 fk1  = u4h8(wsu4[OFF_FK/4  + 64 + wl]);
        f16x8 fv0  = u4h8(wsu4[OFF_FV/4  + wl]);
        f16x8 fv1  = u4h8(wsu4[OFF_FV/4  + 64 + wl]);
        f16x8 fq0  = u4h8(wsu4[OFF_FQ/4  + wl]);
        f16x8 fq1  = u4h8(wsu4[OFF_FQ/4  + 64 + wl]);

        const float* ppf = (const float*)ws32;
        float4 bk0 = *(const float4*)(bk + g4*4);
        float4 bk1 = *(const float4*)(bk + 16 + g4*4);
        float4 bv0 = *(const float4*)(bv + g4*4);
        float4 bv1 = *(const float4*)(bv + 16 + g4*4);
        float4 bq0 = *(const float4*)(ppf + OFF_BQS + g4*4);
        float4 bq1 = *(const float4*)(ppf + OFF_BQS + 16 + g4*4);

        const int srcA = s + 32*(g4 & 1);
        const int srcB = srcA + 16;
        const bool selLo = (g4 < 2);

        #pragma unroll
        for (int jj = 0; jj < 4; jj += 2){
            const int jA = wid + jj*4;
            const int jB = jA + 4;
            // -------- loads (both chains issued together) --------
            f16x8 fupA0 = u4h8(wsu4[OFF_FUP/4 + jA*128 + wl]);
            f16x8 fupA1 = u4h8(wsu4[OFF_FUP/4 + jA*128 + 64 + wl]);
            f16x8 fupB0 = u4h8(wsu4[OFF_FUP/4 + jB*128 + wl]);
            f16x8 fupB1 = u4h8(wsu4[OFF_FUP/4 + jB*128 + 64 + wl]);
            float4 buA0 = *(const float4*)(bup + jA*32 + g4*4);
            float4 buA1 = *(const float4*)(bup + jA*32 + 16 + g4*4);
            float4 buB0 = *(const float4*)(bup + jB*32 + g4*4);
            float4 buB1 = *(const float4*)(bup + jB*32 + 16 + g4*4);
            float4 ppA0 = *(const float4*)(ppf + OFF_PP + jA*32 + g4*4);
            float4 ppA1 = *(const float4*)(ppf + OFF_PP + jA*32 + 16 + g4*4);
            float4 ppB0 = *(const float4*)(ppf + OFF_PP + jB*32 + g4*4);
            float4 ppB1 = *(const float4*)(ppf + OFF_PP + jB*32 + 16 + g4*4);
            uint4 tuA0 = *(const uint4*)(ws32 + OFF_TUP + jA*32 + g4*4);
            uint4 tuA1 = *(const uint4*)(ws32 + OFF_TUP + jA*32 + 16 + g4*4);
            uint4 tuB0 = *(const uint4*)(ws32 + OFF_TUP + jB*32 + g4*4);
            uint4 tuB1 = *(const uint4*)(ws32 + OFF_TUP + jB*32 + 16 + g4*4);

            // -------- up init (bias + x-tail) --------
            f32x4 upA0, upA1, upB0, upB1;
            upA0[0] = fdot2(xtp, tuA0.x, buA0.x); upA0[1] = fdot2(xtp, tuA0.y, buA0.y);
            upA0[2] = fdot2(xtp, tuA0.z, buA0.z); upA0[3] = fdot2(xtp, tuA0.w, buA0.w);
            upA1[0] = fdot2(xtp, tuA1.x, buA1.x); upA1[1] = fdot2(xtp, tuA1.y, buA1.y);
            upA1[2] = fdot2(xtp, tuA1.z, buA1.z); upA1[3] = fdot2(xtp, tuA1.w, buA1.w);
            upB0[0] = fdot2(xtp, tuB0.x, buB0.x); upB0[1] = fdot2(xtp, tuB0.y, buB0.y);
            upB0[2] = fdot2(xtp, tuB0.z, buB0.z); upB0[3] = fdot2(xtp, tuB0.w, buB0.w);
            upB1[0] = fdot2(xtp, tuB1.x, buB1.x); upB1[1] = fdot2(xtp, tuB1.y, buB1.y);
            upB1[2] = fdot2(xtp, tuB1.z, buB1.z); upB1[3] = fdot2(xtp, tuB1.w, buB1.w);

            upA0 = __builtin_amdgcn_mfma_f32_16x16x32_f16(fupA0, ax, upA0, 0,0,0);
            upB0 = __builtin_amdgcn_mfma_f32_16x16x32_f16(fupB0, ax, upB0, 0,0,0);
            upA1 = __builtin_amdgcn_mfma_f32_16x16x32_f16(fupA1, ax, upA1, 0,0,0);
            upB1 = __builtin_amdgcn_mfma_f32_16x16x32_f16(fupB1, ax, upB1, 0,0,0);
            #pragma unroll
            for (int r=0;r<4;r++){
                upA0[r] = lrelu(upA0[r]); upA1[r] = lrelu(upA1[r]);
                upB0[r] = lrelu(upB0[r]); upB1[r] = lrelu(upB1[r]);
            }

            const bool occA = !((bm>>jA)&1u);
            const bool occB = !((bm>>jB)&1u);
            const int rkA = __popc((~bm) & ((1u<<jA)-1u));
            const int rkB = __popc((~bm) & ((1u<<jB)-1u));
            if (occA){
                int rotq = (rkA + s + (s>>2)) & 3;
                uint4 u;
                u.x = pkrtz(upA0[0], upA1[0]); u.y = pkrtz(upA0[1], upA1[1]);
                u.z = pkrtz(upA0[2], upA1[2]); u.w = pkrtz(upA0[3], upA1[3]);
                *(uint4*)&usl[s*QSTRIDE + rkA*16 + ((g4 + rotq)&3)*4] = u;
            }
            if (occB){
                int rotq = (rkB + s + (s>>2)) & 3;
                uint4 u;
                u.x = pkrtz(upB0[0], upB1[0]); u.y = pkrtz(upB0[1], upB1[1]);
                u.z = pkrtz(upB0[2], upB1[2]); u.w = pkrtz(upB0[3], upB1[3]);
                *(uint4*)&usl[s*QSTRIDE + rkB*16 + ((g4 + rotq)&3)*4] = u;
            }
            f16x8 aupA = repack(upA0, upA1, srcA, srcB, selLo);
            f16x8 aupB = repack(upB0, upB1, srcA, srcB, selLo);

            // -------- uu --------
            f32x4 uuA0 = mk4(ppA0), uuA1 = mk4(ppA1);
            f32x4 uuB0 = mk4(ppB0), uuB1 = mk4(ppB1);
            uuA0 = __builtin_amdgcn_mfma_f32_16x16x32_f16(fud0, aupA, uuA0, 0,0,0);
            uuB0 = __builtin_amdgcn_mfma_f32_16x16x32_f16(fud0, aupB, uuB0, 0,0,0);
            uuA1 = __builtin_amdgcn_mfma_f32_16x16x32_f16(fud1, aupA, uuA1, 0,0,0);
            uuB1 = __builtin_amdgcn_mfma_f32_16x16x32_f16(fud1, aupB, uuB1, 0,0,0);
            #pragma unroll
            for (int r=0;r<4;r++){
                uuA0[r] = lrelu(uuA0[r]); uuA1[r] = lrelu(uuA1[r]);
                uuB0[r] = lrelu(uuB0[r]); uuB1[r] = lrelu(uuB1[r]);
            }
            f16x8 auuA = repack(uuA0, uuA1, srcA, srcB, selLo);
            f16x8 auuB = repack(uuB0, uuB1, srcA, srcB, selLo);

            // -------- k, v, q --------
            f32x4 kkA0 = mk4(bk0), kkA1 = mk4(bk1), kkB0 = mk4(bk0), kkB1 = mk4(bk1);
            f32x4 vvA0 = mk4(bv0), vvA1 = mk4(bv1), vvB0 = mk4(bv0), vvB1 = mk4(bv1);
            f32x4 qqA0 = mk4(bq0), qqA1 = mk4(bq1), qqB0 = mk4(bq0), qqB1 = mk4(bq1);
            kkA0 = __builtin_amdgcn_mfma_f32_16x16x32_f16(fk0, auuA, kkA0, 0,0,0);
            kkB0 = __builtin_amdgcn_mfma_f32_16x16x32_f16(fk0, auuB, kkB0, 0,0,0);
            kkA1 = __builtin_amdgcn_mfma_f32_16x16x32_f16(fk1, auuA, kkA1, 0,0,0);
            kkB1 = __builtin_amdgcn_mfma_f32_16x16x32_f16(fk1, auuB, kkB1, 0,0,0);
            vvA0 = __builtin_amdgcn_mfma_f32_16x16x32_f16(fv0, auuA, vvA0, 0,0,0);
            vvB0 = __builtin_amdgcn_mfma_f32_16x16x32_f16(fv0, auuB, vvB0, 0,0,0);
            vvA1 = __builtin_amdgcn_mfma_f32_16x16x32_f16(fv1, auuA, vvA1, 0,0,0);
            vvB1 = __builtin_amdgcn_mfma_f32_16x16x32_f16(fv1, auuB, vvB1, 0,0,0);
            qqA0 = __builtin_amdgcn_mfma_f32_16x16x32_f16(fq0, auuA, qqA0, 0,0,0);
            qqB0 = __builtin_amdgcn_mfma_f32_16x16x32_f16(fq0, auuB, qqB0, 0,0,0);
            qqA1 = __builtin_amdgcn_mfma_f32_16x16x32_f16(fq1, auuA, qqA1, 0,0,0);
            qqB1 = __builtin_amdgcn_mfma_f32_16x16x32_f16(fq1, auuB, qqB1, 0,0,0);

            {
                const int rot = (jA + s + (s>>2)) & 3;
                const int grp = ((g4 + rot)&3)*4;
                uint4 kp, vp;
                kp.x = pkrtz(kkA0[0], kkA1[0]); kp.y = pkrtz(kkA0[1], kkA1[1]);
                kp.z = pkrtz(kkA0[2], kkA1[2]); kp.w = pkrtz(kkA0[3], kkA1[3]);
                vp.x = pkrtz(vvA0[0], vvA1[0]); vp.y = pkrtz(vvA0[1], vvA1[1]);
                vp.z = pkrtz(vvA0[2], vvA1[2]); vp.w = pkrtz(vvA0[3], vvA1[3]);
                *(uint4*)&ksl[s*KSTRIDE + jA*16 + grp] = kp;
                *(uint4*)&vsl[s*KSTRIDE + jA*16 + grp] = vp;
            }
            {
                const int rot = (jB + s + (s>>2)) & 3;
                const int grp = ((g4 + rot)&3)*4;
                uint4 kp, vp;
                kp.x = pkrtz(kkB0[0], kkB1[0]); kp.y = pkrtz(kkB0[1], kkB1[1]);
                kp.z = pkrtz(kkB0[2], kkB1[2]); kp.w = pkrtz(kkB0[3], kkB1[3]);
                vp.x = pkrtz(vvB0[0], vvB1[0]); vp.y = pkrtz(vvB0[1], vvB1[1]);
                vp.z = pkrtz(vvB0[2], vvB1[2]); vp.w = pkrtz(vvB0[3], vvB1[3]);
                *(uint4*)&ksl[s*KSTRIDE + jB*16 + grp] = kp;
                *(uint4*)&vsl[s*KSTRIDE + jB*16 + grp] = vp;
            }
            if (occA){
                int rotq = (rkA + s + (s>>2)) & 3;
                uint4 qp4;
                qp4.x = pkrtz(qqA0[0], qqA1[0]); qp4.y = pkrtz(qqA0[1], qqA1[1]);
                qp4.z = pkrtz(qqA0[2], qqA1[2]); qp4.w = pkrtz(qqA0[3], qqA1[3]);
                *(uint4*)&qsl[s*QSTRIDE + rkA*16 + ((g4 + rotq)&3)*4] = qp4;
            }
            if (occB){
                int rotq = (rkB + s + (s>>2)) & 3;
                uint4 qp4;
                qp4.x = pkrtz(qqB0[0], qqB1[0]); qp4.y = pkrtz(qqB0[1], qqB1[1]);
                qp4.z = pkrtz(qqB0[2], qqB1[2]); qp4.w = pkrtz(qqB0[3], qqB1[3]);
                *(uint4*)&qsl[s*QSTRIDE + rkB*16 + ((g4 + rotq)&3)*4] = qp4;
            }
        }

        // -------- tail: j = 16 (wave 3 only) --------
        if (wid == 3){
            const int j = 16;
            f16x8 fup0 = u4h8(wsu4[OFF_FUP/4 + j*128 + wl]);
            f16x8 fup1 = u4h8(wsu4[OFF_FUP/4 + j*128 + 64 + wl]);
            float4 bu0 = *(const float4*)(bup + j*32 + g4*4);
            float4 bu1 = *(const float4*)(bup + j*32 + 16 + g4*4);
            float4 pp0 = *(const float4*)(ppf + OFF_PP + j*32 + g4*4);
            float4 pp1 = *(const float4*)(ppf + OFF_PP + j*32 + 16 + g4*4);
            uint4 tu0 = *(const uint4*)(ws32 + OFF_TUP + j*32 + g4*4);
            uint4 tu1 = *(const uint4*)(ws32 + OFF_TUP + j*32 + 16 + g4*4);

            f32x4 up0, up1;
            up0[0] = fdot2(xtp, tu0.x, bu0.x); up0[1] = fdot2(xtp, tu0.y, bu0.y);
            up0[2] = fdot2(xtp, tu0.z, bu0.z); up0[3] = fdot2(xtp, tu0.w, bu0.w);
            up1[0] = fdot2(xtp, tu1.x, bu1.x); up1[1] = fdot2(xtp, tu1.y, bu1.y);
            up1[2] = fdot2(xtp, tu1.z, bu1.z); up1[3] = fdot2(xtp, tu1.w, bu1.w);
            up0 = __builtin_amdgcn_mfma_f32_16x16x32_f16(fup0, ax, up0, 0,0,0);
            up1 = __builtin_amdgcn_mfma_f32_16x16x32_f16(fup1, ax, up1, 0,0,0);
            #pragma unroll
            for (int r=0;r<4;r++){ up0[r] = lrelu(up0[r]); up1[r] = lrelu(up1[r]); }

            const bool occ = !((bm>>j)&1u);
            const int rk = __popc((~bm) & ((1u<<j)-1u));
            if (occ){
                int rotq = (rk + s + (s>>2)) & 3;
                uint4 u;
                u.x = pkrtz(up0[0], up1[0]); u.y = pkrtz(up0[1], up1[1]);
                u.z = pkrtz(up0[2], up1[2]); u.w = pkrtz(up0[3], up1[3]);
                *(uint4*)&usl[s*QSTRIDE + rk*16 + ((g4 + rotq)&3)*4] = u;
            }
            f16x8 aup = repack(up0, up1, srcA, srcB, selLo);

            f32x4 uu0 = mk4(pp0), uu1 = mk4(pp1);
            uu0 = __builtin_amdgcn_mfma_f32_16x16x32_f16(fud0, aup, uu0, 0,0,0);
            uu1 = __builtin_amdgcn_mfma_f32_16x16x32_f16(fud1, aup, uu1, 0,0,0);
            #pragma unroll
            for (int r=0;r<4;r++){ uu0[r] = lrelu(uu0[r]); uu1[r] = lrelu(uu1[r]); }
            f16x8 auu = repack(uu0, uu1, srcA, srcB, selLo);

            f32x4 kk0 = mk4(bk0), kk1 = mk4(bk1);
            f32x4 vv0 = mk4(bv0), vv1 = mk4(bv1);
            f32x4 qq0 = mk4(bq0), qq1 = mk4(bq1);
            kk0 = __builtin_amdgcn_mfma_f32_16x16x32_f16(fk0, auu, kk0, 0,0,0);
            kk1 = __builtin_amdgcn_mfma_f32_16x16x32_f16(fk1, auu, kk1, 0,0,0);
            vv0 = __builtin_amdgcn_mfma_f32_16x16x32_f16(fv0, auu, vv0, 0,0,0);
            vv1 = __builtin_amdgcn_mfma_f32_16x16x32_f16(fv1, auu, vv1, 0,0,0);
            qq0 = __builtin_amdgcn_mfma_f32_16x16x32_f16(fq0, auu, qq0, 0,0,0);
            qq1 = __builtin_amdgcn_mfma_f32_16x16x32_f16(fq1, auu, qq1, 0,0,0);

            const int rot = (j + s + (s>>2)) & 3;
            const int grp = ((g4 + rot)&3)*4;
            uint4 kp, vp;
            kp.x = pkrtz(kk0[0], kk1[0]); kp.y = pkrtz(kk0[1], kk1[1]);
            kp.z = pkrtz(kk0[2], kk1[2]); kp.w = pkrtz(kk0[3], kk1[3]);
            vp.x = pkrtz(vv0[0], vv1[0]); vp.y = pkrtz(vv0[1], vv1[1]);
            vp.z = pkrtz(vv0[2], vv1[2]); vp.w = pkrtz(vv0[3], vv1[3]);
            *(uint4*)&ksl[s*KSTRIDE + j*16 + grp] = kp;
            *(uint4*)&vsl[s*KSTRIDE + j*16 + grp] = vp;
            if (occ){
                int rotq = (rk + s + (s>>2)) & 3;
                uint4 qp4;
                qp4.x = pkrtz(qq0[0], qq1[0]); qp4.y = pkrtz(qq0[1], qq1[1]);
                qp4.z = pkrtz(qq0[2], qq1[2]); qp4.w = pkrtz(qq0[3], qq1[3]);
                *(uint4*)&qsl[s*QSTRIDE + rk*16 + ((g4 + rotq)&3)*4] = qp4;
            }
        }
    }
    __syncthreads();

    // ---------------- phase 2a: ALL 256 lanes = 128 pairs x 2 key-halves ----
    const int half  = tid >> 7;           // wave-uniform: waves 0-1 / 2-3
    const int pr    = tid & 127;
    const int s2 = pr >> 3, q = pr & 7;
    const int kbase = half*8;             // half0: keys 0..8*, half1: keys 8..16
                                          // (*key 8 dup for scores; PV wt zeroed)
    unsigned qw[16];
    {
        int rot = (q + s2 + (s2>>2)) & 3;
        const unsigned* base = qsl + s2*QSTRIDE + q*16;
        #pragma unroll
        for (int a=0;a<4;a++){
            uint4 t = *(const uint4*)(base + ((a + rot)&3)*4);
            qw[4*a]=t.x; qw[4*a+1]=t.y; qw[4*a+2]=t.z; qw[4*a+3]=t.w;
        }
    }
    float scl[9];
    #pragma unroll
    for (int i=0;i<9;i++){
        int kj = kbase + i;
        unsigned kw[16];
        int rot = (kj + s2 + (s2>>2)) & 3;
        const unsigned* kb = ksl + s2*KSTRIDE + kj*16;
        #pragma unroll
        for (int a=0;a<4;a++){
            uint4 t = *(const uint4*)(kb + ((a + rot)&3)*4);
            kw[4*a]=t.x; kw[4*a+1]=t.y; kw[4*a+2]=t.z; kw[4*a+3]=t.w;
        }
        float s0=0.f,s1=0.f,s2a=0.f,s3=0.f;
        #pragma unroll
        for (int p=0;p<16;p+=4){
            s0  = fdot2(qw[p],   kw[p],   s0);
            s1  = fdot2(qw[p+1], kw[p+1], s1);
            s2a = fdot2(qw[p+2], kw[p+2], s2a);
            s3  = fdot2(qw[p+3], kw[p+3], s3);
        }
        scl[i] = (s0+s1)+(s2a+s3);
    }
    __syncthreads();                      // all k reads done -> ksl dead
    // scores -> ksl, stride 21 (coprime 32: conflict-free b32)
    #pragma unroll
    for (int i=0;i<9;i++) ksl[pr*21 + kbase + i] = __float_as_uint(scl[i]);
    __syncthreads();
    float sc[JN];
    #pragma unroll
    for (int kj=0;kj<JN;kj++) sc[kj] = __uint_as_float(ksl[pr*21 + kj]);
    float m = sc[0];
    #pragma unroll
    for (int kj=1;kj<JN;kj++) m = fmaxf(m, sc[kj]);
    float sum = 0.f;
    #pragma unroll
    for (int kj=0;kj<JN;kj++) sum += __expf(sc[kj]-m);
    float ri = 1.0f/sum;

    // PV over own keys only (o partial); half0's i==8 weight zeroed
    unsigned o[16];
    #pragma unroll
    for (int p=0;p<16;p++) o[p] = 0u;
    #pragma unroll
    for (int i=0;i<9;i++){
        int kj = kbase + i;
        float w = __expf(scl[i]-m)*ri;
        if (i==8 && half==0) w = 0.f;
        unsigned w2 = pkrtz(w, w);
        unsigned vw[16];
        int rot = (kj + s2 + (s2>>2)) & 3;
        const unsigned* vb = vsl + s2*KSTRIDE + kj*16;
        #pragma unroll
        for (int a=0;a<4;a++){
            uint4 t = *(const uint4*)(vb + ((a + rot)&3)*4);
            vw[4*a]=t.x; vw[4*a+1]=t.y; vw[4*a+2]=t.z; vw[4*a+3]=t.w;
        }
        #pragma unroll
        for (int p=0;p<16;p++) o[p] = pkfma(w2, vw[p], o[p]);
    }
    __syncthreads();                      // all v reads done -> vsl dead
    {
        int rot = (pr>>1)&3;
        unsigned* dst = vsl + half*2048 + pr*16;
        *(uint4*)&dst[((0+rot)&3)*4] = make_uint4(o[0],o[1],o[2],o[3]);
        *(uint4*)&dst[((1+rot)&3)*4] = make_uint4(o[4],o[5],o[6],o[7]);
        *(uint4*)&dst[((2+rot)&3)*4] = make_uint4(o[8],o[9],o[10],o[11]);
        *(uint4*)&dst[((3+rot)&3)*4] = make_uint4(o[12],o[13],o[14],o[15]);
    }
    __syncthreads();

    // ---------------- phase 2b: all 4 waves, d1/d2 as batched MFMAs ----------
    {
        const int rid = wl & 15, g4b = wl >> 4;
        const uint4* wsu4 = (const uint4*)ws32;
        f16x8 fd1_0 = u4h8(wsu4[OFF_FD1/4 + wl]);
        f16x8 fd1_1 = u4h8(wsu4[OFF_FD1/4 + 64 + wl]);
        f16x8 fd2_0 = u4h8(wsu4[OFF_FD2/4 + wl]);
        f16x8 fd2_1 = u4h8(wsu4[OFF_FD2/4 + 64 + wl]);
        float4 bd10 = *(const float4*)(bd1 + g4b*4);
        float4 bd11 = *(const float4*)(bd1 + 16 + g4b*4);
        float4 bd20 = *(const float4*)(bd2 + g4b*4);
        float4 bd21 = *(const float4*)(bd2 + 16 + g4b*4);
        float4 ws0  = *(const float4*)(Ws + g4b*4);
        float4 ws1  = *(const float4*)(Ws + 16 + g4b*4);
        const float bsv = bs[0];
        const int srcA = rid + 32*(g4b & 1);
        const int srcB = srcA + 16;
        const bool selLo = (g4b < 2);

        #pragma unroll
        for (int gg=0; gg<2; gg++){
            const int rowg = (wid*2 + gg)*16 + rid;       // 0..127
            int roto = (rowg>>1)&3;
            uint4 a4 = *(const uint4*)&vsl[rowg*16 + ((g4b + roto)&3)*4];
            uint4 b4 = *(const uint4*)&vsl[2048 + rowg*16 + ((g4b + roto)&3)*4];
            f16x8 bo = u4h8(a4) + u4h8(b4);               // merge o partials

            f32x4 t0 = mk4(bd10), t1 = mk4(bd11);
            t0 = __builtin_amdgcn_mfma_f32_16x16x32_f16(fd1_0, bo, t0, 0,0,0);
            t1 = __builtin_amdgcn_mfma_f32_16x16x32_f16(fd1_1, bo, t1, 0,0,0);
            #pragma unroll
            for (int r=0;r<4;r++){ t0[r] = lrelu(t0[r]); t1[r] = lrelu(t1[r]); }
            f16x8 bt = repack(t0, t1, srcA, srcB, selLo);

            const int s2b = rowg >> 3, qb = rowg & 7;
            int rotq = (qb + s2b + (s2b>>2)) & 3;
            uint4 ur = *(const uint4*)&usl[s2b*QSTRIDE + qb*16 + ((g4b + rotq)&3)*4];
            unsigned urr[4] = {ur.x, ur.y, ur.z, ur.w};
            f32x4 z0, z1;
            {
                h2v r0 = u2h(urr[0]), r1 = u2h(urr[1]), r2 = u2h(urr[2]), r3 = u2h(urr[3]);
                z0[0] = (float)r0.x + bd20.x; z1[0] = (float)r0.y + bd21.x;
                z0[1] = (float)r1.x + bd20.y; z1[1] = (float)r1.y + bd21.y;
                z0[2] = (float)r2.x + bd20.z; z1[2] = (float)r2.y + bd21.z;
                z0[3] = (float)r3.x + bd20.w; z1[3] = (float)r3.y + bd21.w;
            }
            z0 = __builtin_amdgcn_mfma_f32_16x16x32_f16(fd2_0, bt, z0, 0,0,0);
            z1 = __builtin_amdgcn_mfma_f32_16x16x32_f16(fd2_1, bt, z1, 0,0,0);

            float yp = z0[0]*ws0.x + z0[1]*ws0.y + z0[2]*ws0.z + z0[3]*ws0.w
                     + z1[0]*ws1.x + z1[1]*ws1.y + z1[2]*ws1.z + z1[3]*ws1.w;
            yp += __shfl_xor(yp, 16, 64);
            yp += __shfl_xor(yp, 32, 64);
            if (g4b == 0 && sb + s2b < B){
                float y = yp + bsv;
                out[((size_t)(sb + s2b))*8 + qb] = 1.0f/(1.0f + __expf(-y));
            }
        }
    }
}

extern "C" void kernel_launch(void* const* d_in, const int* in_sizes, int n_in,
                              void* d_out, int out_size, void* d_ws, size_t ws_size,
                              hipStream_t stream) {
    (void)n_in; (void)out_size; (void)ws_size;
    const float* x   = (const float*)d_in[0];
    const void*  m   = d_in[1];
    const float* pos = (const float*)d_in[2];
    const float* Wup = (const float*)d_in[3];  const float* bup = (const float*)d_in[4];
    const float* Wud = (const float*)d_in[5];  const float* bud = (const float*)d_in[6];
    const float* Wq  = (const float*)d_in[7];  const float* bq  = (const float*)d_in[8];
    const float* Wk  = (const float*)d_in[9];  const float* bk  = (const float*)d_in[10];
    const float* Wv  = (const float*)d_in[11]; const float* bv  = (const float*)d_in[12];
    const float* Wd1 = (const float*)d_in[13]; const float* bd1 = (const float*)d_in[14];
    const float* Wd2 = (const float*)d_in[15]; const float* bd2 = (const float*)d_in[16];
    const float* Ws  = (const float*)d_in[17]; const float* bs  = (const float*)d_in[18];
    float* out = (float*)d_out;
    int B = in_sizes[0] / (JN*2);

    unsigned char* wsb = (unsigned char*)d_ws;
    unsigned* ws32  = (unsigned*)wsb;
    unsigned* bmask = (unsigned*)(wsb + HDR_BYTES);

    prep_kernel<<<(B+255)/256, 256, 0, stream>>>(m, pos, Wup, Wud, bud, Wq, bq,
                                                 Wk, Wv, Wd1, Wd2, ws32, bmask, B);
    fused_kernel<<<(B+15)/16, 256, 0, stream>>>(x, bmask, ws32, bup, bk, bv,
                                                bd1, bd2, Ws, bs, out, B);
}